// Round 4
// baseline (928.585 us; speedup 1.0000x reference)
//
#include <hip/hip_runtime.h>
#include <cstdint>
#include <cstddef>

typedef int int4v __attribute__((ext_vector_type(4)));
typedef signed char schar;

#define DEVI __device__ __forceinline__

DEVI void load_lds16(const void* g, void* l) {
  __builtin_amdgcn_global_load_lds(
      (const __attribute__((address_space(1))) void*)g,
      (__attribute__((address_space(3))) void*)l, 16, 0, 0);
}

#define SB0() __builtin_amdgcn_sched_barrier(0)
#define BAR() __builtin_amdgcn_s_barrier()
#define LGKM(n)                                                   \
  do {                                                            \
    asm volatile("s_waitcnt lgkmcnt(" #n ")" ::: "memory");       \
    SB0();                                                        \
  } while (0)
#define VMW(n)                                                    \
  do {                                                            \
    asm volatile("s_waitcnt vmcnt(" #n ")" ::: "memory");         \
    SB0();                                                        \
  } while (0)

// ---- pack int32 -> int8, linear (4 elems/thread) ----
__global__ __launch_bounds__(256) void pack_i8(const int* __restrict__ src,
                                               signed char* __restrict__ dst,
                                               int n4) {
  int i = blockIdx.x * 256 + threadIdx.x;
  if (i >= n4) return;
  int4v v = ((const int4v*)src)[i];
  int p = (v.x & 255) | ((v.y & 255) << 8) | ((v.z & 255) << 16) | (v.w << 24);
  ((int*)dst)[i] = p;
}

// ---- pack + transpose: w[K][N] int32 -> wT[N][K] int8, 64x64 LDS tiles ----
__global__ __launch_bounds__(256) void pack_wT(const int* __restrict__ w,
                                               signed char* __restrict__ wT,
                                               int K, int N) {
  __shared__ signed char t[64][68];
  int n0 = blockIdx.x * 64, k0 = blockIdx.y * 64;
  int tr = threadIdx.x >> 6, tc = threadIdx.x & 63;
#pragma unroll
  for (int i = 0; i < 16; ++i) {
    int r = i * 4 + tr;
    t[r][tc] = (signed char)w[(size_t)(k0 + r) * N + n0 + tc];
  }
  __syncthreads();
#pragma unroll
  for (int i = 0; i < 16; ++i) {
    int r = i * 4 + tr;
    wT[(size_t)(n0 + r) * K + k0 + tc] = t[tc][r];
  }
}

// ---- 256x256 wave-split-K i8 GEMM: C[M,N] = A[M,K] * BT[N,K]^T ----
// 8 waves = 2x2 spatial quadrants (128x128 each) x 2 K-halves.
// BK=128 B/tile = 2 MFMA K-steps; wave wk computes k-step wk only.
// Per wave per tile: 16 ds_read_b128, 64 MFMA -> CU LDS 1536+512 cy < MFMA
// 2611 cy (MFMA-bound; previous 128x64 wave shape was LDS-bound).
// One barrier + one vmcnt(0) per tile; waves drift to overlap LDS and MFMA.
// Epilogue: 2-round LDS reduce of the wk halves, then requant/store.
// LDS: A[2][256][128] @0, B[2][256][128] @64K (128 KiB dynamic).
template <int EPI>
__global__ __launch_bounds__(512, 2) void gemmK(
    const schar* __restrict__ A, const schar* __restrict__ BT,
    int M, int N, int K, const int* __restrict__ bias_i,
    const float* __restrict__ alphaP, const float* __restrict__ betaP,
    const float* __restrict__ bias_f, schar* __restrict__ outQ,
    float* __restrict__ outF) {
  extern __shared__ schar lds[];

  const int tid = threadIdx.x;
  const int wid = tid >> 6, lane = tid & 63;
  const int wk = wid >> 2;                  // K-half
  const int wr = (wid >> 1) & 1, wc = wid & 1;
  const int q = wid & 3;                    // spatial quadrant id
  const int l16 = lane & 15, l4 = lane >> 4;

  // XCD-bijective block swizzle (nwg % 8 == 0 for both GEMMs)
  const int gx = gridDim.x;
  const int nwg = gx * gridDim.y;
  const int bid = blockIdx.y * gx + blockIdx.x;
  const int swz = (bid & 7) * (nwg >> 3) + (bid >> 3);
  const int rowBase = (swz / gx) * 256;
  const int colBase = (swz % gx) * 256;
  const int NT = K >> 7;

  // pin scalar params; drain SMEM before counted lgkm waits
  const float alpha = alphaP[0];
  const float beta = (EPI == 0) ? betaP[0] : 0.f;
  asm volatile("" ::"s"(alpha), "s"(beta));
  LGKM(0);

  // staging source pointers (pre-swizzled global slot; LDS dest linear)
  const schar* gA[4];
  const schar* gB[4];
#pragma unroll
  for (int c = 0; c < 4; ++c) {
    int off = c * 8192 + tid * 16;
    int r = off >> 7;
    int gs = ((off >> 4) & 7) ^ (r & 7);
    gA[c] = A + (size_t)(rowBase + r) * K + gs * 16;
    gB[c] = BT + (size_t)(colBase + r) * K + gs * 16;
  }

  auto stage = [&](int buf, int t) {
#pragma unroll
    for (int c = 0; c < 4; ++c)
      load_lds16(gA[c] + (size_t)t * 128,
                 lds + buf * 32768 + c * 8192 + wid * 1024);
#pragma unroll
    for (int c = 0; c < 4; ++c)
      load_lds16(gB[c] + (size_t)t * 128,
                 lds + 65536 + buf * 32768 + c * 8192 + wid * 1024);
  };

  // fragment read offsets; row&7 == l16&7 so swizzle slot is lane-const
  const int so = ((wk * 4 + l4) ^ (l16 & 7)) * 16 + l16 * 128;
  const int ao = wr * 16384 + so;  // + mi*2048
  const int bo = wc * 16384 + so;  // + ni*2048

  int4v acc[8][8] = {};
  int4v aF[8], bF[8];

#define RD_A(I0, Ab)                                                   \
  _Pragma("unroll") for (int mi = 0; mi < 4; ++mi) aF[(I0) + mi] =     \
      *(const int4v*)((Ab) + ao + ((I0) + mi) * 2048)
#define RD_B(I0, Bb)                                                   \
  _Pragma("unroll") for (int ni = 0; ni < 4; ++ni) bF[(I0) + ni] =     \
      *(const int4v*)((Bb) + bo + ((I0) + ni) * 2048)
#define MM(MI, NI)                                        \
  acc[MI][NI] = __builtin_amdgcn_mfma_i32_16x16x64_i8(    \
      aF[MI], bF[NI], acc[MI][NI], 0, 0, 0)

  // prologue: stage tile 0, drain, barrier
  stage(0, 0);
  VMW(0);
  BAR();

  for (int T = 0; T < NT; ++T) {
    const int cb = T & 1, ob = cb ^ 1;
    const schar* Ab = lds + cb * 32768;
    const schar* Bb = lds + 65536 + cb * 32768;

    // phase 0: frags 0..3, 16 MFMA
    RD_A(0, Ab);
    RD_B(0, Bb);
    LGKM(0);
    __builtin_amdgcn_s_setprio(1);
#pragma unroll
    for (int mi = 0; mi < 4; ++mi)
#pragma unroll
      for (int ni = 0; ni < 4; ++ni) MM(mi, ni);
    __builtin_amdgcn_s_setprio(0);

    // stage next tile early (hides HBM latency under rest of tile)
    if (T + 1 < NT) stage(ob, T + 1);

    // phase 1: frags 4..7, 48 MFMA
    RD_A(4, Ab);
    RD_B(4, Bb);
    LGKM(0);
    __builtin_amdgcn_s_setprio(1);
#pragma unroll
    for (int mi = 0; mi < 4; ++mi)
#pragma unroll
      for (int ni = 4; ni < 8; ++ni) MM(mi, ni);
#pragma unroll
    for (int mi = 4; mi < 8; ++mi)
#pragma unroll
      for (int ni = 0; ni < 8; ++ni) MM(mi, ni);
    __builtin_amdgcn_s_setprio(0);

    VMW(0);  // next tile fully resident
    BAR();   // buffer swap; also orders staged-LDS visibility
  }

  // ---- reduce wk halves via LDS (2 rounds of 128 KiB), then epilogue ----
  // C/D frag: col = lane&15, row = (lane>>4)*4 + j
#pragma unroll
  for (int r = 0; r < 2; ++r) {
    __syncthreads();
    if (wk == 1) {
#pragma unroll
      for (int mi = 0; mi < 4; ++mi)
#pragma unroll
        for (int ni = 0; ni < 8; ++ni)
          *(int4v*)(lds + q * 32768 + (mi * 8 + ni) * 1024 + lane * 16) =
              acc[r * 4 + mi][ni];
    }
    __syncthreads();
    if (wk == 0) {
#pragma unroll
      for (int mi = 0; mi < 4; ++mi) {
        int row = rowBase + wr * 128 + (r * 4 + mi) * 16 + l4 * 4;
#pragma unroll
        for (int ni = 0; ni < 8; ++ni) {
          int4v p =
              *(const int4v*)(lds + q * 32768 + (mi * 8 + ni) * 1024 +
                              lane * 16);
          int4v s = acc[r * 4 + mi][ni] + p;
          int col = colBase + wc * 128 + ni * 16 + l16;
          if (EPI == 0) {
            float bt = (float)bias_i[col] * beta;
#pragma unroll
            for (int j = 0; j < 4; ++j) {
              float h = (float)s[j] * alpha + bt;
              h = fmaxf(h, 0.f);
              h = rintf(h);  // numpy round-half-even
              h = fminf(h, 127.f);
              outQ[(size_t)(row + j) * N + col] = (schar)h;
            }
          } else {
            float bv = bias_f[col];
#pragma unroll
            for (int j = 0; j < 4; ++j)
              outF[(size_t)(row + j) * N + col] = (float)s[j] * alpha + bv;
          }
        }
      }
    }
  }
#undef RD_A
#undef RD_B
#undef MM
}

extern "C" void kernel_launch(void* const* d_in, const int* in_sizes, int n_in,
                              void* d_out, int out_size, void* d_ws,
                              size_t ws_size, hipStream_t stream) {
  const int M = 16384, H = 1024, I = 4096;  // B*S = 16384
  const int* hidden = (const int*)d_in[0];
  const int* w_fc = (const int*)d_in[1];
  const int* b_fc = (const int*)d_in[2];
  const float* alpha_fc = (const float*)d_in[3];
  const float* beta_fc = (const float*)d_in[4];
  const int* w_proj = (const int*)d_in[5];
  const float* b_proj = (const float*)d_in[6];
  const float* alpha_proj = (const float*)d_in[7];
  float* out = (float*)d_out;

  signed char* hq = (signed char*)d_ws;     // [M][I]  64 MB
  signed char* aP = hq + (size_t)M * I;     // [M][H]  16 MB
  signed char* wfcT = aP + (size_t)M * H;   // [I][H]   4 MB (w_fc^T)
  signed char* wpT = wfcT + (size_t)I * H;  // [H][I]   4 MB (w_proj^T)

  hipFuncSetAttribute((const void*)gemmK<0>,
                      hipFuncAttributeMaxDynamicSharedMemorySize, 131072);
  hipFuncSetAttribute((const void*)gemmK<1>,
                      hipFuncAttributeMaxDynamicSharedMemorySize, 131072);

  pack_i8<<<(M * H / 4 + 255) / 256, 256, 0, stream>>>(hidden, aP, M * H / 4);
  pack_wT<<<dim3(I / 64, H / 64), 256, 0, stream>>>(w_fc, wfcT, H, I);
  pack_wT<<<dim3(H / 64, I / 64), 256, 0, stream>>>(w_proj, wpT, I, H);

  gemmK<0><<<dim3(I / 256, M / 256), 512, 131072, stream>>>(
      aP, wfcT, M, I, H, b_fc, alpha_fc, beta_fc, nullptr, hq, nullptr);
  gemmK<1><<<dim3(H / 256, M / 256), 512, 131072, stream>>>(
      hq, wpT, M, H, I, nullptr, alpha_proj, nullptr, b_proj, nullptr, out);
}

// Round 5
// 174.608 us; speedup vs baseline: 5.3181x; 5.3181x over previous
//
#include <hip/hip_runtime.h>
#include <cstdint>
#include <cstddef>

typedef int int4v __attribute__((ext_vector_type(4)));
typedef signed char schar;

#define DEVI __device__ __forceinline__

DEVI void load_lds16(const void* g, void* l) {
  __builtin_amdgcn_global_load_lds(
      (const __attribute__((address_space(1))) void*)g,
      (__attribute__((address_space(3))) void*)l, 16, 0, 0);
}

#define SB0() __builtin_amdgcn_sched_barrier(0)
#define BAR() __builtin_amdgcn_s_barrier()
#define LGKM(n)                                                   \
  do {                                                            \
    asm volatile("s_waitcnt lgkmcnt(" #n ")" ::: "memory");       \
    SB0();                                                        \
  } while (0)
#define VMW(n)                                                    \
  do {                                                            \
    asm volatile("s_waitcnt vmcnt(" #n ")" ::: "memory");         \
    SB0();                                                        \
  } while (0)

// ---- pack int32 -> int8, linear (4 elems/thread) ----
__global__ __launch_bounds__(256) void pack_i8(const int* __restrict__ src,
                                               signed char* __restrict__ dst,
                                               int n4) {
  int i = blockIdx.x * 256 + threadIdx.x;
  if (i >= n4) return;
  int4v v = ((const int4v*)src)[i];
  int p = (v.x & 255) | ((v.y & 255) << 8) | ((v.z & 255) << 16) | (v.w << 24);
  ((int*)dst)[i] = p;
}

// ---- pack + transpose: w[K][N] int32 -> wT[N][K] int8, 64x64 LDS tiles ----
__global__ __launch_bounds__(256) void pack_wT(const int* __restrict__ w,
                                               signed char* __restrict__ wT,
                                               int K, int N) {
  __shared__ signed char t[64][68];
  int n0 = blockIdx.x * 64, k0 = blockIdx.y * 64;
  int tr = threadIdx.x >> 6, tc = threadIdx.x & 63;
#pragma unroll
  for (int i = 0; i < 16; ++i) {
    int r = i * 4 + tr;
    t[r][tc] = (signed char)w[(size_t)(k0 + r) * N + n0 + tc];
  }
  __syncthreads();
#pragma unroll
  for (int i = 0; i < 16; ++i) {
    int r = i * 4 + tr;
    wT[(size_t)(n0 + r) * K + k0 + tc] = t[tc][r];
  }
}

// ---- 256x256 relaxed-schedule i8 GEMM: C[M,N] = A[M,K] * BT[N,K]^T ----
// 8 waves (2Mx4N), 128x64 out/wave, acc[8][4]=128 AGPR (R2's proven budget).
// ONE barrier + one vmcnt(0) per K-tile (BK=128 B = 2 MFMA K-steps):
//   rd kk0 (12 ds_read_b128) | stage T+1 -> other buf | lgkm(0) | 32 MFMA
//   rd kk1 (same regs, WAR via scoreboard) | lgkm(0) | 32 MFMA
//   vmcnt(0) | barrier
// No mid-tile barriers: 2 waves/SIMD drift so one wave's reads hide under
// the other's MFMA. All reads drained (lgkm0) before each wave's barrier
// arrival => staging T+2 into buffer cb after the barrier is WAR-safe.
template <int EPI>
__global__ __launch_bounds__(512, 2) void gemmR(
    const schar* __restrict__ A, const schar* __restrict__ BT,
    int M, int N, int K, const int* __restrict__ bias_i,
    const float* __restrict__ alphaP, const float* __restrict__ betaP,
    const float* __restrict__ bias_f, schar* __restrict__ outQ,
    float* __restrict__ outF) {
  extern __shared__ schar lds[];

  const int tid = threadIdx.x;
  const int wid = tid >> 6, lane = tid & 63;
  const int wr = wid >> 2, wc = wid & 3;  // 2M x 4N waves
  const int l16 = lane & 15, l4 = lane >> 4;

  // XCD-bijective block swizzle (nwg % 8 == 0 for both GEMMs)
  const int gx = gridDim.x;
  const int nwg = gx * gridDim.y;
  const int bid = blockIdx.y * gx + blockIdx.x;
  const int swz = (bid & 7) * (nwg >> 3) + (bid >> 3);
  const int rowBase = (swz / gx) * 256;
  const int colBase = (swz % gx) * 256;
  const int NT = K >> 7;

  // pin scalar params; drain SMEM before counted lgkm waits
  const float alpha = alphaP[0];
  const float beta = (EPI == 0) ? betaP[0] : 0.f;
  asm volatile("" ::"s"(alpha), "s"(beta));
  LGKM(0);

  // staging source pointers (pre-swizzled global slot; LDS dest linear)
  const schar* gA[4];
  const schar* gB[4];
#pragma unroll
  for (int c = 0; c < 4; ++c) {
    int off = c * 8192 + tid * 16;
    int r = off >> 7;
    int gs = ((off >> 4) & 7) ^ (r & 7);
    gA[c] = A + (size_t)(rowBase + r) * K + gs * 16;
    gB[c] = BT + (size_t)(colBase + r) * K + gs * 16;
  }

  auto stage = [&](int buf, int t) {
#pragma unroll
    for (int c = 0; c < 4; ++c)
      load_lds16(gA[c] + (size_t)t * 128,
                 lds + buf * 32768 + c * 8192 + wid * 1024);
#pragma unroll
    for (int c = 0; c < 4; ++c)
      load_lds16(gB[c] + (size_t)t * 128,
                 lds + 65536 + buf * 32768 + c * 8192 + wid * 1024);
  };

  // fragment read offsets; row&7 == l16&7 so swizzle slot is lane-const
  const int so0 = ((0 + l4) ^ (l16 & 7)) * 16 + l16 * 128;  // kk=0
  const int so1 = ((4 + l4) ^ (l16 & 7)) * 16 + l16 * 128;  // kk=1

  int4v acc[8][4] = {};
  int4v aF[8], bF[4];

#define RDA(SO, Ab)                                                  \
  _Pragma("unroll") for (int mi = 0; mi < 8; ++mi) aF[mi] =          \
      *(const int4v*)((Ab) + wr * 16384 + mi * 2048 + (SO))
#define RDB(SO, Bb)                                                  \
  _Pragma("unroll") for (int ni = 0; ni < 4; ++ni) bF[ni] =          \
      *(const int4v*)((Bb) + wc * 8192 + ni * 2048 + (SO))
#define MMALL()                                                      \
  do {                                                               \
    __builtin_amdgcn_s_setprio(1);                                   \
    _Pragma("unroll") for (int mi = 0; mi < 8; ++mi)                 \
        _Pragma("unroll") for (int ni = 0; ni < 4; ++ni) acc[mi][ni] = \
        __builtin_amdgcn_mfma_i32_16x16x64_i8(aF[mi], bF[ni],        \
                                              acc[mi][ni], 0, 0, 0); \
    __builtin_amdgcn_s_setprio(0);                                   \
  } while (0)

  // prologue: stage tile 0, drain, barrier
  stage(0, 0);
  VMW(0);
  BAR();

  for (int T = 0; T < NT; ++T) {
    const int cb = T & 1, ob = cb ^ 1;
    const schar* Ab = lds + cb * 32768;
    const schar* Bb = lds + 65536 + cb * 32768;

    // kk = 0
    RDA(so0, Ab);
    RDB(so0, Bb);
    if (T + 1 < NT) stage(ob, T + 1);  // hides HBM under this tile's MFMA
    LGKM(0);
    MMALL();
    // kk = 1 (reuse frag regs; scoreboard enforces WAR vs kk0 MFMAs)
    RDA(so1, Ab);
    RDB(so1, Bb);
    LGKM(0);
    MMALL();

    VMW(0);  // own staging chunk landed
    BAR();   // publish buffer ob; all waves' reads of cb done
  }

  // ---- epilogue; C/D frag: col = lane&15, row = (lane>>4)*4 + j ----
  if (EPI == 0) {
#pragma unroll
    for (int MI = 0; MI < 8; ++MI) {
      int row = rowBase + wr * 128 + MI * 16 + l4 * 4;
#pragma unroll
      for (int NI = 0; NI < 4; ++NI) {
        int col = colBase + wc * 64 + NI * 16 + l16;
        float bt = (float)bias_i[col] * beta;
#pragma unroll
        for (int j = 0; j < 4; ++j) {
          float h = (float)acc[MI][NI][j] * alpha + bt;
          h = fmaxf(h, 0.f);
          h = rintf(h);  // numpy round-half-even
          h = fminf(h, 127.f);
          outQ[(size_t)(row + j) * N + col] = (schar)h;
        }
      }
    }
  } else {
#pragma unroll
    for (int MI = 0; MI < 8; ++MI) {
      int row = rowBase + wr * 128 + MI * 16 + l4 * 4;
#pragma unroll
      for (int NI = 0; NI < 4; ++NI) {
        int col = colBase + wc * 64 + NI * 16 + l16;
        float bv = bias_f[col];
#pragma unroll
        for (int j = 0; j < 4; ++j)
          outF[(size_t)(row + j) * N + col] =
              (float)acc[MI][NI][j] * alpha + bv;
      }
    }
  }
#undef RDA
#undef RDB
#undef MMALL
}

extern "C" void kernel_launch(void* const* d_in, const int* in_sizes, int n_in,
                              void* d_out, int out_size, void* d_ws,
                              size_t ws_size, hipStream_t stream) {
  const int M = 16384, H = 1024, I = 4096;  // B*S = 16384
  const int* hidden = (const int*)d_in[0];
  const int* w_fc = (const int*)d_in[1];
  const int* b_fc = (const int*)d_in[2];
  const float* alpha_fc = (const float*)d_in[3];
  const float* beta_fc = (const float*)d_in[4];
  const int* w_proj = (const int*)d_in[5];
  const float* b_proj = (const float*)d_in[6];
  const float* alpha_proj = (const float*)d_in[7];
  float* out = (float*)d_out;

  signed char* hq = (signed char*)d_ws;     // [M][I]  64 MB
  signed char* aP = hq + (size_t)M * I;     // [M][H]  16 MB
  signed char* wfcT = aP + (size_t)M * H;   // [I][H]   4 MB (w_fc^T)
  signed char* wpT = wfcT + (size_t)I * H;  // [H][I]   4 MB (w_proj^T)

  hipFuncSetAttribute((const void*)gemmR<0>,
                      hipFuncAttributeMaxDynamicSharedMemorySize, 131072);
  hipFuncSetAttribute((const void*)gemmR<1>,
                      hipFuncAttributeMaxDynamicSharedMemorySize, 131072);

  pack_i8<<<(M * H / 4 + 255) / 256, 256, 0, stream>>>(hidden, aP, M * H / 4);
  pack_wT<<<dim3(I / 64, H / 64), 256, 0, stream>>>(w_fc, wfcT, H, I);
  pack_wT<<<dim3(H / 64, I / 64), 256, 0, stream>>>(w_proj, wpT, I, H);

  gemmR<0><<<dim3(I / 256, M / 256), 512, 131072, stream>>>(
      aP, wfcT, M, I, H, b_fc, alpha_fc, beta_fc, nullptr, hq, nullptr);
  gemmR<1><<<dim3(H / 256, M / 256), 512, 131072, stream>>>(
      hq, wpT, M, H, I, nullptr, alpha_proj, nullptr, b_proj, nullptr, out);
}